// Round 4
// baseline (357.811 us; speedup 1.0000x reference)
//
#include <hip/hip_runtime.h>
#include <math.h>

// ---------------- problem constants ----------------
constexpr int Bn  = 128;      // batch
constexpr int Kd  = 65536;    // magnitude dim (phase half of feats is zeros)
constexpr int F1  = 128;
constexpr int F2  = 64;
constexpr int NM  = 3;        // number of ops matrices
constexpr int Qd  = 256;
constexpr int NCH = 256;      // split-K chunks for big GEMM
constexpr int KC  = 256;      // k per chunk
constexpr int MSZ = 256 * 256;

// quintic (Muon) Newton-Schulz coefficients
#define QA 3.4445f
#define QB (-4.7750f)
#define QC 2.0315f

// ---------------- ws layout (float offsets) ----------------
constexpr size_t OFF_H1P  = 0;                                   // 4,194,304
constexpr size_t OFF_H1   = OFF_H1P + (size_t)NCH * Bn * F1;     // 16384
constexpr size_t OFF_SEL  = OFF_H1 + (size_t)Bn * F1;            // 128 (int)
constexpr size_t OFF_PART = OFF_SEL + 128;                       // 192 -> pad 256
constexpr size_t OFF_XA   = OFF_PART + 256;
constexpr size_t OFF_XB   = OFF_XA + (size_t)NM * MSZ;
constexpr size_t OFF_AM   = OFF_XB + (size_t)NM * MSZ;

// ---------------- K1: split-K magnitude GEMM ----------------
// 256 blocks x 512 threads. Block = chunk ch: C[128b][128j] partial over k in [ch*256, ch*256+256).
// 8 kt subtiles of 32 k; k-major LDS [32][132]; reg-prefetch of kt+1 overlaps compute.
__global__ __launch_bounds__(512) void k_gemm1(const float* __restrict__ sp,
                                               const float* __restrict__ W1,
                                               float* __restrict__ h1p) {
  __shared__ float As[32][132];   // As[kq][row] = |sp[row][k0+kt*32+kq]|
  __shared__ float Ws[32][132];   // Ws[kq][col] = W1[col][k0+kt*32+kq]
  const int t  = threadIdx.x;
  const int ch = blockIdx.x;
  const size_t k0 = (size_t)ch * KC;
  const int r0 = (t >> 4) * 4;    // 4 output rows (batch)
  const int c0 = (t & 15) * 8;    // 8 output cols (F1)
  const int srow = t >> 3;        // staging: rows srow, srow+64
  const int squad = t & 7;        // staging: k-quad

  float acc[4][8];
#pragma unroll
  for (int r = 0; r < 4; ++r)
#pragma unroll
    for (int c = 0; c < 8; ++c) acc[r][c] = 0.f;

  float4 ra0, ra1, rw0, rw1;
  {
    const size_t kb = k0 + squad * 4;
    ra0 = *(const float4*)(sp + (size_t)srow * Kd + kb);
    ra1 = *(const float4*)(sp + (size_t)(srow + 64) * Kd + kb);
    rw0 = *(const float4*)(W1 + (size_t)srow * (2 * Kd) + kb);
    rw1 = *(const float4*)(W1 + (size_t)(srow + 64) * (2 * Kd) + kb);
  }

#pragma unroll
  for (int kt = 0; kt < 8; ++kt) {
    __syncthreads();  // previous compute done; LDS reusable
#pragma unroll
    for (int e = 0; e < 4; ++e) {
      As[squad * 4 + e][srow]      = fabsf((&ra0.x)[e]);
      As[squad * 4 + e][srow + 64] = fabsf((&ra1.x)[e]);
      Ws[squad * 4 + e][srow]      = (&rw0.x)[e];
      Ws[squad * 4 + e][srow + 64] = (&rw1.x)[e];
    }
    __syncthreads();
    if (kt < 7) {  // prefetch next subtile; lands during compute below
      const size_t kb = k0 + (kt + 1) * 32 + squad * 4;
      ra0 = *(const float4*)(sp + (size_t)srow * Kd + kb);
      ra1 = *(const float4*)(sp + (size_t)(srow + 64) * Kd + kb);
      rw0 = *(const float4*)(W1 + (size_t)srow * (2 * Kd) + kb);
      rw1 = *(const float4*)(W1 + (size_t)(srow + 64) * (2 * Kd) + kb);
    }
#pragma unroll 8
    for (int q = 0; q < 32; ++q) {
      const float4 av = *(const float4*)&As[q][r0];
      const float4 w0 = *(const float4*)&Ws[q][c0];
      const float4 w1 = *(const float4*)&Ws[q][c0 + 4];
      const float a[4] = {av.x, av.y, av.z, av.w};
      const float w[8] = {w0.x, w0.y, w0.z, w0.w, w1.x, w1.y, w1.z, w1.w};
#pragma unroll
      for (int r = 0; r < 4; ++r)
#pragma unroll
        for (int c = 0; c < 8; ++c) acc[r][c] += a[r] * w[c];
    }
  }

  float* outp = h1p + (size_t)ch * (Bn * F1);
#pragma unroll
  for (int r = 0; r < 4; ++r) {
    float4 o0 = {acc[r][0], acc[r][1], acc[r][2], acc[r][3]};
    float4 o1 = {acc[r][4], acc[r][5], acc[r][6], acc[r][7]};
    *(float4*)(outp + (r0 + r) * F1 + c0)     = o0;
    *(float4*)(outp + (r0 + r) * F1 + c0 + 4) = o1;
  }
}

// ---------------- K1b: reduce partials + bias + relu ----------------
__global__ __launch_bounds__(256) void k_red(const float* __restrict__ h1p,
                                             const float* __restrict__ b1,
                                             float* __restrict__ h1) {
  const int t = threadIdx.x;
  const int ol = t & 63;
  const int g = t >> 6;
  const int o = blockIdx.x * 64 + ol;
  double s = 0.0;
#pragma unroll 8
  for (int c = g * 64; c < g * 64 + 64; ++c)
    s += (double)h1p[(size_t)c * (Bn * F1) + o];
  __shared__ double red[4][64];
  red[g][ol] = s;
  __syncthreads();
  if (g == 0) {
    const double v = red[0][ol] + red[1][ol] + red[2][ol] + red[3][ol];
    const float r = (float)v + b1[o & 127];
    h1[o] = fmaxf(r, 0.f);
  }
}

// ---------------- K2: small MLP + syndrome + selection ----------------
__global__ __launch_bounds__(256) void k_mlp(const float* __restrict__ h1,
                                             const float* __restrict__ W2,
                                             const float* __restrict__ b2,
                                             const float* __restrict__ W3,
                                             const float* __restrict__ b3,
                                             int* __restrict__ sel) {
  const int t = threadIdx.x;
  const int b0 = blockIdx.x * 16;
  __shared__ float h2s[16 * 64];
  for (int o = t; o < 16 * 64; o += 256) {
    const int bl = o >> 6, j = o & 63;
    const float* hr = h1 + (b0 + bl) * F1;
    const float* wr = W2 + j * F1;
    float s = b2[j];
    for (int k = 0; k < F1; ++k) s += hr[k] * wr[k];
    h2s[o] = fmaxf(s, 0.f);
  }
  __syncthreads();
  if (t < 16) {
    const int b = b0 + t;
    float best = -1.f;
    int bi = 0;
    bool needed = false;
    for (int j = 0; j < 8; ++j) {
      double s = (double)b3[j];
      const float* wr = W3 + j * F2;
      for (int k = 0; k < F2; ++k) s += (double)h2s[t * F2 + k] * (double)wr[k];
      const float a = fabsf((float)s);
      if (a > 1e-4f) needed = true;
      if (a > best) { best = a; bi = j; }
    }
    sel[b] = needed ? (bi % NM) : -1;
  }
}

// ---------------- NS setup: partial sum of squares (192 blocks) ----------------
__global__ __launch_bounds__(256) void k_sumsq(const float* __restrict__ ops,
                                               float* __restrict__ part) {
  const int m = blockIdx.x >> 6, g = blockIdx.x & 63;
  const int t = threadIdx.x;
  const float4 v = ((const float4*)(ops + (size_t)m * MSZ + g * 1024))[t];
  __shared__ float red[256];
  red[t] = v.x * v.x + v.y * v.y + v.z * v.z + v.w * v.w;
  __syncthreads();
  for (int o = 128; o > 0; o >>= 1) {
    if (t < o) red[t] += red[t + o];
    __syncthreads();
  }
  if (t == 0) part[m * 64 + g] = red[0];
}

// ---------------- NS setup: redundant scale reduce + scale (192 blocks) ----------------
__global__ __launch_bounds__(256) void k_scale(const float* __restrict__ ops,
                                               const float* __restrict__ part,
                                               float* __restrict__ X) {
  const int m = blockIdx.x >> 6, g = blockIdx.x & 63;
  const int t = threadIdx.x;
  __shared__ float sbc;
  float v = (t < 64) ? part[m * 64 + t] : 0.f;
  if (t < 64) {
#pragma unroll
    for (int o = 32; o > 0; o >>= 1) v += __shfl_down(v, o, 64);
  }
  if (t == 0) sbc = 1.f / (0.15f * sqrtf(v));  // 1/(1.2 * 2||F||/sqrt(256))
  __syncthreads();
  const float sc = sbc;
  float4 v4 = ((const float4*)(ops + (size_t)m * MSZ + g * 1024))[t];
  v4.x *= sc; v4.y *= sc; v4.z *= sc; v4.w *= sc;
  ((float4*)(X + (size_t)m * MSZ + g * 1024))[t] = v4;
}

// ---------------- NS phase A: A = X^T X (192 blocks x 512 thr, 4 A-rows each) ----------------
__global__ __launch_bounds__(512) void k_pA(const float* __restrict__ X,
                                            float* __restrict__ A) {
  const int m = blockIdx.x >> 6, g = blockIdx.x & 63, i0 = g * 4;
  const int t = threadIdx.x, tq = t >> 6, tc = t & 63;
  const float* Xm = X + (size_t)m * MSZ;
  float* Am = A + (size_t)m * MSZ;
  __shared__ float pt[256][4];        // pt[k][i] = X[k][i0+i]
  __shared__ float red[8][64][17];

  if (t < 256) {
    const float4 cv = *(const float4*)(Xm + t * 256 + i0);
    pt[t][0] = cv.x; pt[t][1] = cv.y; pt[t][2] = cv.z; pt[t][3] = cv.w;
  }
  __syncthreads();

  const float4* X4 = (const float4*)Xm;
  float a[4][4];
#pragma unroll
  for (int i = 0; i < 4; ++i)
#pragma unroll
    for (int j = 0; j < 4; ++j) a[i][j] = 0.f;

  const int kbase = tq * 32;
#pragma unroll 16
  for (int kk = 0; kk < 32; ++kk) {
    const int k = kbase + kk;
    const float4 xv = X4[k * 64 + tc];          // X[k][4tc..4tc+3]
    const float4 pv = *(const float4*)pt[k];    // X[k][i0..i0+3]
    a[0][0] += pv.x*xv.x; a[0][1] += pv.x*xv.y; a[0][2] += pv.x*xv.z; a[0][3] += pv.x*xv.w;
    a[1][0] += pv.y*xv.x; a[1][1] += pv.y*xv.y; a[1][2] += pv.y*xv.z; a[1][3] += pv.y*xv.w;
    a[2][0] += pv.z*xv.x; a[2][1] += pv.z*xv.y; a[2][2] += pv.z*xv.z; a[2][3] += pv.z*xv.w;
    a[3][0] += pv.w*xv.x; a[3][1] += pv.w*xv.y; a[3][2] += pv.w*xv.z; a[3][3] += pv.w*xv.w;
  }
  float* rr = &red[tq][tc][0];
#pragma unroll
  for (int i = 0; i < 4; ++i)
#pragma unroll
    for (int j = 0; j < 4; ++j) rr[i * 4 + j] = a[i][j];
  __syncthreads();

  if (t < 256) {
    const int tc2 = t >> 2, j = t & 3;
#pragma unroll
    for (int i = 0; i < 4; ++i) {
      const int x = i * 4 + j;
      float s = 0.f;
#pragma unroll
      for (int q = 0; q < 8; ++q) s += red[q][tc2][x];
      Am[(i0 + i) * 256 + t] = s;
    }
  }
}

// ---------------- NS phase B: Y=XA rows, Z=YA rows, combine (192 x 512) ----------------
__global__ __launch_bounds__(512) void k_pB(const float* __restrict__ X,
                                            const float* __restrict__ A,
                                            float* __restrict__ Xn,
                                            const int quint) {
  const int m = blockIdx.x >> 6, g = blockIdx.x & 63, i0 = g * 4;
  const int t = threadIdx.x, tq = t >> 6, tc = t & 63;
  const float* Xm = X + (size_t)m * MSZ;
  const float* Am = A + (size_t)m * MSZ;
  float* Xo = Xn + (size_t)m * MSZ;
  __shared__ float xr[4][260];        // xr[k>>6][(k&63)*4+i] = X[i0+i][k]
  __shared__ float yr[4][260];
  __shared__ float red[8][64][17];

  if (t < 256) {
    const int ri = t >> 6, f4 = t & 63;
    const float4 xv = *(const float4*)(Xm + (i0 + ri) * 256 + f4 * 4);
#pragma unroll
    for (int e = 0; e < 4; ++e) {
      const int k = f4 * 4 + e;
      xr[k >> 6][(k & 63) * 4 + ri] = (&xv.x)[e];
    }
  }
  __syncthreads();

  const float4* A4 = (const float4*)Am;
  const int kbase = tq * 32;

  // ---- stage 1: Y rows ----
  {
    float a[4][4];
#pragma unroll
    for (int i = 0; i < 4; ++i)
#pragma unroll
      for (int j = 0; j < 4; ++j) a[i][j] = 0.f;
#pragma unroll 16
    for (int kk = 0; kk < 32; ++kk) {
      const int k = kbase + kk;
      const float4 av = A4[k * 64 + tc];
      const float4 pv = *(const float4*)&xr[k >> 6][(k & 63) * 4];
      a[0][0] += pv.x*av.x; a[0][1] += pv.x*av.y; a[0][2] += pv.x*av.z; a[0][3] += pv.x*av.w;
      a[1][0] += pv.y*av.x; a[1][1] += pv.y*av.y; a[1][2] += pv.y*av.z; a[1][3] += pv.y*av.w;
      a[2][0] += pv.z*av.x; a[2][1] += pv.z*av.y; a[2][2] += pv.z*av.z; a[2][3] += pv.z*av.w;
      a[3][0] += pv.w*av.x; a[3][1] += pv.w*av.y; a[3][2] += pv.w*av.z; a[3][3] += pv.w*av.w;
    }
    float* rr = &red[tq][tc][0];
#pragma unroll
    for (int i = 0; i < 4; ++i)
#pragma unroll
      for (int j = 0; j < 4; ++j) rr[i * 4 + j] = a[i][j];
  }
  __syncthreads();

  float yv[4] = {0.f, 0.f, 0.f, 0.f};
  if (t < 256) {
    const int tc2 = t >> 2, jj = t & 3;
#pragma unroll
    for (int i = 0; i < 4; ++i) {
      const int x = i * 4 + jj;
      float s = 0.f;
#pragma unroll
      for (int q = 0; q < 8; ++q) s += red[q][tc2][x];
      yv[i] = s;
    }
  }

  if (!quint) {  // cubic: X' = 1.5*X - 0.5*Y
    if (t < 256) {
#pragma unroll
      for (int i = 0; i < 4; ++i)
        Xo[(i0 + i) * 256 + t] = 1.5f * Xm[(i0 + i) * 256 + t] - 0.5f * yv[i];
    }
    return;
  }

  __syncthreads();  // red reads done before overwrite; yr not yet valid
  if (t < 256) {
#pragma unroll
    for (int i = 0; i < 4; ++i)
      yr[t >> 6][(t & 63) * 4 + i] = yv[i];
  }
  __syncthreads();

  // ---- stage 2: Z rows ----
  {
    float a[4][4];
#pragma unroll
    for (int i = 0; i < 4; ++i)
#pragma unroll
      for (int j = 0; j < 4; ++j) a[i][j] = 0.f;
#pragma unroll 16
    for (int kk = 0; kk < 32; ++kk) {
      const int k = kbase + kk;
      const float4 av = A4[k * 64 + tc];
      const float4 pv = *(const float4*)&yr[k >> 6][(k & 63) * 4];
      a[0][0] += pv.x*av.x; a[0][1] += pv.x*av.y; a[0][2] += pv.x*av.z; a[0][3] += pv.x*av.w;
      a[1][0] += pv.y*av.x; a[1][1] += pv.y*av.y; a[1][2] += pv.y*av.z; a[1][3] += pv.y*av.w;
      a[2][0] += pv.z*av.x; a[2][1] += pv.z*av.y; a[2][2] += pv.z*av.z; a[2][3] += pv.z*av.w;
      a[3][0] += pv.w*av.x; a[3][1] += pv.w*av.y; a[3][2] += pv.w*av.z; a[3][3] += pv.w*av.w;
    }
    float* rr = &red[tq][tc][0];
#pragma unroll
    for (int i = 0; i < 4; ++i)
#pragma unroll
      for (int j = 0; j < 4; ++j) rr[i * 4 + j] = a[i][j];
  }
  __syncthreads();

  if (t < 256) {
    const int tc2 = t >> 2, jj = t & 3;
#pragma unroll
    for (int i = 0; i < 4; ++i) {
      const int x = i * 4 + jj;
      float zv = 0.f;
#pragma unroll
      for (int q = 0; q < 8; ++q) zv += red[q][tc2][x];
      Xo[(i0 + i) * 256 + t] =
          QA * Xm[(i0 + i) * 256 + t] + QB * yv[i] + QC * zv;
    }
  }
}

// ---------------- K4: output assembly ----------------
__global__ __launch_bounds__(256) void k_out(const float* __restrict__ sp,
                                             const float* __restrict__ P,
                                             const int* __restrict__ sel,
                                             float* __restrict__ out) {
  const int t = threadIdx.x;
  if (blockIdx.x < 128) {
    const int b = blockIdx.x;
    __shared__ float hd[256];
    hd[t] = sp[(size_t)b * Kd + t];
    __syncthreads();
    const int s = sel[b];
    if (s < 0) {
      out[(size_t)b * Kd + t] = hd[t];
    } else {
      const float4* prow = (const float4*)(P + (size_t)s * MSZ + t * 256);
      float acc = 0.f;
#pragma unroll 8
      for (int j4 = 0; j4 < 64; ++j4) {
        const float4 p = prow[j4];
        acc += p.x * hd[4 * j4 + 0] + p.y * hd[4 * j4 + 1] +
               p.z * hd[4 * j4 + 2] + p.w * hd[4 * j4 + 3];
      }
      out[(size_t)b * Kd + t] = hd[t] + 0.1f * acc;
    }
  } else {
    const int ci = blockIdx.x - 128;
    const float4* in4 = (const float4*)sp;
    float4* out4 = (float4*)out;
    const int total = Bn * (Kd / 4);
    for (int i = ci * 256 + t; i < total; i += 2048 * 256) {
      const int pos = i & ((Kd / 4) - 1);
      if (pos >= Qd / 4) out4[i] = in4[i];
    }
  }
}

// ---------------- host ----------------
extern "C" void kernel_launch(void* const* d_in, const int* in_sizes, int n_in,
                              void* d_out, int out_size, void* d_ws, size_t ws_size,
                              hipStream_t stream) {
  (void)in_sizes; (void)n_in; (void)out_size; (void)ws_size;
  const float* sp = (const float*)d_in[0];
  const float* W1 = (const float*)d_in[1];
  const float* b1 = (const float*)d_in[2];
  const float* W2 = (const float*)d_in[3];
  const float* b2 = (const float*)d_in[4];
  const float* W3 = (const float*)d_in[5];
  const float* b3 = (const float*)d_in[6];
  const float* ops = (const float*)d_in[7];
  float* out = (float*)d_out;
  float* ws = (float*)d_ws;

  float* h1p  = ws + OFF_H1P;
  float* h1   = ws + OFF_H1;
  int*   sel  = (int*)(ws + OFF_SEL);
  float* part = ws + OFF_PART;
  float* Xa   = ws + OFF_XA;
  float* Xb   = ws + OFF_XB;
  float* Am   = ws + OFF_AM;

  k_gemm1<<<NCH, 512, 0, stream>>>(sp, W1, h1p);
  k_red<<<256, 256, 0, stream>>>(h1p, b1, h1);
  k_mlp<<<8, 256, 0, stream>>>(h1, W2, b2, W3, b3, sel);
  k_sumsq<<<192, 256, 0, stream>>>(ops, part);
  k_scale<<<192, 256, 0, stream>>>(ops, part, Xa);

  float* X = Xa;
  float* Xn = Xb;
  for (int it = 0; it < 12; ++it) {
    k_pA<<<192, 512, 0, stream>>>(X, Am);
    k_pB<<<192, 512, 0, stream>>>(X, Am, Xn, (it < 8) ? 1 : 0);
    float* tmp = X; X = Xn; Xn = tmp;
  }

  k_out<<<128 + 2048, 256, 0, stream>>>(sp, X, sel, out);
}

// Round 5
// 245.884 us; speedup vs baseline: 1.4552x; 1.4552x over previous
//
#include <hip/hip_runtime.h>
#include <math.h>

// ---------------- problem constants ----------------
constexpr int Bn  = 128;      // batch
constexpr int Kd  = 65536;    // magnitude dim (phase half of feats is zeros)
constexpr int F1  = 128;
constexpr int F2  = 64;
constexpr int NM  = 3;        // number of ops matrices
constexpr int Qd  = 256;
constexpr int NCH = 256;      // split-K chunks for big GEMM
constexpr int KC  = 256;      // k per chunk
constexpr int MSZ = 256 * 256;

// Muon (growth) and convergent quintic Newton-Schulz coefficients
#define MA 3.4445f
#define MB (-4.7750f)
#define MC 2.0315f
#define CA 1.875f
#define CB (-1.25f)
#define CC 0.375f

// ---------------- ws layout (float offsets) ----------------
constexpr size_t OFF_H1P  = 0;                                   // 4,194,304
constexpr size_t OFF_H1   = OFF_H1P + (size_t)NCH * Bn * F1;     // 16384
constexpr size_t OFF_SEL  = OFF_H1 + (size_t)Bn * F1;            // 128 (int)
constexpr size_t OFF_PART = OFF_SEL + 128;                       // 24 -> pad 64
constexpr size_t OFF_XA   = OFF_PART + 64;
constexpr size_t OFF_XB   = OFF_XA + (size_t)NM * MSZ;
constexpr size_t OFF_AB   = OFF_XB + (size_t)NM * MSZ;           // bf16: NM*MSZ ushorts

// ---------------- bf16 helpers (RNE) ----------------
__device__ __forceinline__ unsigned int pk2(float x, float y) {
  unsigned int bx = __float_as_uint(x), by = __float_as_uint(y);
  bx = (bx + 0x7FFFu + ((bx >> 16) & 1u)) >> 16;
  by = (by + 0x7FFFu + ((by >> 16) & 1u)) >> 16;
  return bx | (by << 16);
}
__device__ __forceinline__ float blo(unsigned int v) { return __uint_as_float(v << 16); }
__device__ __forceinline__ float bhi(unsigned int v) { return __uint_as_float(v & 0xFFFF0000u); }

// ---------------- K1: split-K magnitude GEMM ----------------
// 256 blocks x 512 threads. Block = chunk ch over k in [ch*256, ch*256+256).
// 8x8 thread tiles ({r0,r0+64}x{c0,c0+64} quads), 2-way k-split (h = q-range),
// LDS 1.0 B/FMA, conflicts <=2-way, k-split combined through LDS in 2 rounds.
__global__ __launch_bounds__(512) void k_gemm1(const float* __restrict__ sp,
                                               const float* __restrict__ W1,
                                               float* __restrict__ h1p) {
  __shared__ float smem[2][32][132];   // [0]=As, [1]=Ws; aliased as combine buf
  float (*As)[132] = smem[0];
  float (*Ws)[132] = smem[1];
  const int t  = threadIdx.x;
  const int ch = blockIdx.x;
  const size_t k0 = (size_t)ch * KC;
  const int u = t & 255;
  const int h = t >> 8;            // k-half: q = h*16 + qq within each subtile
  const int r0 = (u >> 4) * 4;     // rows r0..r0+3 and r0+64..r0+67
  const int c0 = (u & 15) * 4;     // cols c0..c0+3 and c0+64..c0+67
  const int srow = t >> 3;         // staging rows srow, srow+64
  const int squad = t & 7;         // staging k-quad

  float acc[2][2][4][4];
#pragma unroll
  for (int ri = 0; ri < 2; ++ri)
#pragma unroll
    for (int ci = 0; ci < 2; ++ci)
#pragma unroll
      for (int i = 0; i < 4; ++i)
#pragma unroll
        for (int j = 0; j < 4; ++j) acc[ri][ci][i][j] = 0.f;

  float4 ra0, ra1, rw0, rw1;
  {
    const size_t kb = k0 + squad * 4;
    ra0 = *(const float4*)(sp + (size_t)srow * Kd + kb);
    ra1 = *(const float4*)(sp + (size_t)(srow + 64) * Kd + kb);
    rw0 = *(const float4*)(W1 + (size_t)srow * (2 * Kd) + kb);
    rw1 = *(const float4*)(W1 + (size_t)(srow + 64) * (2 * Kd) + kb);
  }

#pragma unroll
  for (int kt = 0; kt < 8; ++kt) {
    __syncthreads();
#pragma unroll
    for (int e = 0; e < 4; ++e) {
      As[squad * 4 + e][srow]      = fabsf((&ra0.x)[e]);
      As[squad * 4 + e][srow + 64] = fabsf((&ra1.x)[e]);
      Ws[squad * 4 + e][srow]      = (&rw0.x)[e];
      Ws[squad * 4 + e][srow + 64] = (&rw1.x)[e];
    }
    __syncthreads();
    if (kt < 7) {
      const size_t kb = k0 + (kt + 1) * 32 + squad * 4;
      ra0 = *(const float4*)(sp + (size_t)srow * Kd + kb);
      ra1 = *(const float4*)(sp + (size_t)(srow + 64) * Kd + kb);
      rw0 = *(const float4*)(W1 + (size_t)srow * (2 * Kd) + kb);
      rw1 = *(const float4*)(W1 + (size_t)(srow + 64) * (2 * Kd) + kb);
    }
#pragma unroll
    for (int qq = 0; qq < 16; ++qq) {
      const int q = h * 16 + qq;
      const float4 a0 = *(const float4*)&As[q][r0];
      const float4 a1 = *(const float4*)&As[q][r0 + 64];
      const float4 w0 = *(const float4*)&Ws[q][c0];
      const float4 w1 = *(const float4*)&Ws[q][c0 + 64];
      const float av[2][4] = {{a0.x, a0.y, a0.z, a0.w}, {a1.x, a1.y, a1.z, a1.w}};
      const float wv[2][4] = {{w0.x, w0.y, w0.z, w0.w}, {w1.x, w1.y, w1.z, w1.w}};
#pragma unroll
      for (int ri = 0; ri < 2; ++ri)
#pragma unroll
        for (int ci = 0; ci < 2; ++ci)
#pragma unroll
          for (int i = 0; i < 4; ++i)
#pragma unroll
            for (int j = 0; j < 4; ++j)
              acc[ri][ci][i][j] += av[ri][i] * wv[ci][j];
    }
  }

  // combine the two k-halves through LDS (2 rounds of 128 slots, stride 66)
  float* comb = (float*)smem;
  float* af = &acc[0][0][0][0];
#pragma unroll
  for (int r = 0; r < 2; ++r) {
    __syncthreads();
    if (h == 1 && ((u >> 7) == r)) {
      const int slot = u & 127;
#pragma unroll
      for (int p = 0; p < 32; ++p)
        *(float2*)&comb[slot * 66 + p * 2] = make_float2(af[p * 2], af[p * 2 + 1]);
    }
    __syncthreads();
    if (h == 0 && ((u >> 7) == r)) {
      const int slot = u & 127;
#pragma unroll
      for (int p = 0; p < 64; ++p) af[p] += comb[slot * 66 + p];
    }
  }

  if (h == 0) {
    float* outp = h1p + (size_t)ch * (Bn * F1);
#pragma unroll
    for (int ri = 0; ri < 2; ++ri)
#pragma unroll
      for (int i = 0; i < 4; ++i) {
        const int row = r0 + ri * 64 + i;
#pragma unroll
        for (int ci = 0; ci < 2; ++ci) {
          *(float4*)&outp[row * F1 + c0 + ci * 64] =
              make_float4(acc[ri][ci][i][0], acc[ri][ci][i][1],
                          acc[ri][ci][i][2], acc[ri][ci][i][3]);
        }
      }
  }
}

// ---------------- K1b: reduce partials + bias + relu ----------------
__global__ __launch_bounds__(256) void k_red(const float* __restrict__ h1p,
                                             const float* __restrict__ b1,
                                             float* __restrict__ h1) {
  const int t = threadIdx.x;
  const int ol = t & 63;
  const int g = t >> 6;
  const int o = blockIdx.x * 64 + ol;
  double s = 0.0;
#pragma unroll 8
  for (int c = g * 64; c < g * 64 + 64; ++c)
    s += (double)h1p[(size_t)c * (Bn * F1) + o];
  __shared__ double red[4][64];
  red[g][ol] = s;
  __syncthreads();
  if (g == 0) {
    const double v = red[0][ol] + red[1][ol] + red[2][ol] + red[3][ol];
    const float r = (float)v + b1[o & 127];
    h1[o] = fmaxf(r, 0.f);
  }
}

// ---------------- K2: small MLP + syndrome + selection ----------------
__global__ __launch_bounds__(256) void k_mlp(const float* __restrict__ h1,
                                             const float* __restrict__ W2,
                                             const float* __restrict__ b2,
                                             const float* __restrict__ W3,
                                             const float* __restrict__ b3,
                                             int* __restrict__ sel) {
  const int t = threadIdx.x;
  const int b0 = blockIdx.x * 16;
  __shared__ float h2s[16 * 64];
  for (int o = t; o < 16 * 64; o += 256) {
    const int bl = o >> 6, j = o & 63;
    const float* hr = h1 + (b0 + bl) * F1;
    const float* wr = W2 + j * F1;
    float s = b2[j];
    for (int k = 0; k < F1; ++k) s += hr[k] * wr[k];
    h2s[o] = fmaxf(s, 0.f);
  }
  __syncthreads();
  if (t < 16) {
    const int b = b0 + t;
    float best = -1.f;
    int bi = 0;
    bool needed = false;
    for (int j = 0; j < 8; ++j) {
      double s = (double)b3[j];
      const float* wr = W3 + j * F2;
      for (int k = 0; k < F2; ++k) s += (double)h2s[t * F2 + k] * (double)wr[k];
      const float a = fabsf((float)s);
      if (a > 1e-4f) needed = true;
      if (a > best) { best = a; bi = j; }
    }
    sel[b] = needed ? (bi % NM) : -1;
  }
}

// ---------------- NS phase A: A = X^T X (bf16 out, symmetric tiles) ----------------
// grid = NM*36 blocks (upper 32x32 tiles), 512 threads, 8-way k-split.
// Diagonal tiles also emit trace partials (for the iter-0 scale).
__global__ __launch_bounds__(512) void k_pA(const float* __restrict__ Xs,
                                            unsigned short* __restrict__ Ab,
                                            float* __restrict__ part) {
  const int bid = blockIdx.x;
  const int m = bid / 36;
  int I = 0;
  {
    int rem = bid % 36;
    while (rem >= 8 - I) { rem -= 8 - I; ++I; }
    I = I;  // row
    // J computed below from rem
    // (rem now in [0, 8-I))
    // store J in rem+I
    int J_ = I + rem;
    // pass via variables
    I = (I & 7) | (J_ << 8);  // pack to avoid extra vars (unpacked next)
  }
  const int J = I >> 8;
  I = I & 7;
  const float* Xm = Xs + (size_t)m * MSZ;
  unsigned short* Am = Ab + (size_t)m * MSZ;
  __shared__ unsigned int PI2[16][260];   // col-pair packed bf16, [c2][k]
  __shared__ unsigned int PJ2[16][260];
  __shared__ float red[7][64][17];
  __shared__ float tr8[8];
  const int t = threadIdx.x;

  // stage both 32-col panels as bf16 pairs
#pragma unroll
  for (int it = 0; it < 4; ++it) {
    const int idx = it * 512 + t;
    const int k = idx >> 3, c4 = idx & 7;
    const float4 vI = *(const float4*)&Xm[k * 256 + I * 32 + c4 * 4];
    PI2[c4 * 2 + 0][k] = pk2(vI.x, vI.y);
    PI2[c4 * 2 + 1][k] = pk2(vI.z, vI.w);
    const float4 vJ = *(const float4*)&Xm[k * 256 + J * 32 + c4 * 4];
    PJ2[c4 * 2 + 0][k] = pk2(vJ.x, vJ.y);
    PJ2[c4 * 2 + 1][k] = pk2(vJ.z, vJ.w);
  }
  __syncthreads();

  const int h = t >> 6, u = t & 63, ur = u >> 3, uc = u & 7;
  float acc[4][4];
#pragma unroll
  for (int i = 0; i < 4; ++i)
#pragma unroll
    for (int j = 0; j < 4; ++j) acc[i][j] = 0.f;

  const int kb = h * 32;
#pragma unroll 8
  for (int kk = 0; kk < 32; ++kk) {
    const int k = kb + kk;
    const unsigned int p0 = PI2[ur * 2][k], p1 = PI2[ur * 2 + 1][k];
    const unsigned int q0 = PJ2[uc * 2][k], q1 = PJ2[uc * 2 + 1][k];
    const float a0 = blo(p0), a1 = bhi(p0), a2 = blo(p1), a3 = bhi(p1);
    const float b0 = blo(q0), b1 = bhi(q0), b2 = blo(q1), b3 = bhi(q1);
    acc[0][0] += a0 * b0; acc[0][1] += a0 * b1; acc[0][2] += a0 * b2; acc[0][3] += a0 * b3;
    acc[1][0] += a1 * b0; acc[1][1] += a1 * b1; acc[1][2] += a1 * b2; acc[1][3] += a1 * b3;
    acc[2][0] += a2 * b0; acc[2][1] += a2 * b1; acc[2][2] += a2 * b2; acc[2][3] += a2 * b3;
    acc[3][0] += a3 * b0; acc[3][1] += a3 * b1; acc[3][2] += a3 * b2; acc[3][3] += a3 * b3;
  }
  if (h) {
    float* rr = &red[h - 1][u][0];
#pragma unroll
    for (int i = 0; i < 4; ++i)
#pragma unroll
      for (int j = 0; j < 4; ++j) rr[i * 4 + j] = acc[i][j];
  }
  __syncthreads();
  if (h == 0) {
#pragma unroll
    for (int i = 0; i < 4; ++i)
#pragma unroll
      for (int j = 0; j < 4; ++j) {
        float s = acc[i][j];
#pragma unroll
        for (int q = 0; q < 7; ++q) s += red[q][u][i * 4 + j];
        acc[i][j] = s;
      }
    const int gr = I * 32 + ur * 4, gc = J * 32 + uc * 4;
#pragma unroll
    for (int i = 0; i < 4; ++i) {
      *(unsigned int*)&Am[(gr + i) * 256 + gc]     = pk2(acc[i][0], acc[i][1]);
      *(unsigned int*)&Am[(gr + i) * 256 + gc + 2] = pk2(acc[i][2], acc[i][3]);
    }
    if (I != J) {
#pragma unroll
      for (int j = 0; j < 4; ++j) {
        *(unsigned int*)&Am[(gc + j) * 256 + gr]     = pk2(acc[0][j], acc[1][j]);
        *(unsigned int*)&Am[(gc + j) * 256 + gr + 2] = pk2(acc[2][j], acc[3][j]);
      }
    } else if (ur == uc) {
      tr8[ur] = acc[0][0] + acc[1][1] + acc[2][2] + acc[3][3];
    }
  }
  if (I == J) {
    __syncthreads();
    if (t == 0) {
      float s = 0.f;
#pragma unroll
      for (int q = 0; q < 8; ++q) s += tr8[q];
      part[m * 8 + I] = s;
    }
  }
}

// ---------------- NS phase B: X' = ca*X + cb*(X A) + cc*(X A A) ----------------
// grid = 192 (4-row strips), 512 threads, 8-way k-split, A streamed as bf16.
// first=1: X-src is raw C; coefficients folded with 1/s and 1/s^2 (A holds C^T C).
__global__ __launch_bounds__(512) void k_pB(const float* __restrict__ Xs,
                                            const unsigned short* __restrict__ Ab,
                                            const float* __restrict__ part,
                                            float* __restrict__ Xn,
                                            const float qa, const float qb, const float qc,
                                            const int first) {
  const int m = blockIdx.x >> 6, g = blockIdx.x & 63, i0 = g * 4;
  const float* Xm = Xs + (size_t)m * MSZ;
  const unsigned short* Am = Ab + (size_t)m * MSZ;
  float* Xo = Xn + (size_t)m * MSZ;
  const int t = threadIdx.x, h = t >> 6, u = t & 63;
  __shared__ float xs[4][260];
  __shared__ float ys[4][260];
  __shared__ float red[7][64][17];

  float ca = qa, cb = qb, cc = qc;
  if (first) {
    float tr = 0.f;
#pragma unroll
    for (int q = 0; q < 8; ++q) tr += part[m * 8 + q];
    const float s = 0.15f * sqrtf(tr);     // 1.2 * 2*||C||_F/sqrt(256)
    const float is = 1.f / s, is2 = is * is;
    ca = qa * is;
    cb = qb * is * is2;        // qb / s^3
    cc = qc * is * is2 * is2;  // qc / s^5
  }

  if (t < 256) {  // stage 4-row X strip (fp32)
    const int r = t >> 6, cq = t & 63;
    *(float4*)&xs[r][cq * 4] = *(const float4*)&Xm[(i0 + r) * 256 + cq * 4];
  }
  __syncthreads();

  const int kb = h * 32;
  float accY[4][4];
#pragma unroll
  for (int i = 0; i < 4; ++i)
#pragma unroll
    for (int j = 0; j < 4; ++j) accY[i][j] = 0.f;
#pragma unroll 8
  for (int kk = 0; kk < 32; ++kk) {
    const int k = kb + kk;
    const uint2 aw = *(const uint2*)&Am[k * 256 + u * 4];
    const float b0 = blo(aw.x), b1 = bhi(aw.x), b2 = blo(aw.y), b3 = bhi(aw.y);
    const float x0 = xs[0][k], x1 = xs[1][k], x2 = xs[2][k], x3 = xs[3][k];
    accY[0][0] += x0 * b0; accY[0][1] += x0 * b1; accY[0][2] += x0 * b2; accY[0][3] += x0 * b3;
    accY[1][0] += x1 * b0; accY[1][1] += x1 * b1; accY[1][2] += x1 * b2; accY[1][3] += x1 * b3;
    accY[2][0] += x2 * b0; accY[2][1] += x2 * b1; accY[2][2] += x2 * b2; accY[2][3] += x2 * b3;
    accY[3][0] += x3 * b0; accY[3][1] += x3 * b1; accY[3][2] += x3 * b2; accY[3][3] += x3 * b3;
  }
  if (h) {
    float* rr = &red[h - 1][u][0];
#pragma unroll
    for (int i = 0; i < 4; ++i)
#pragma unroll
      for (int j = 0; j < 4; ++j) rr[i * 4 + j] = accY[i][j];
  }
  __syncthreads();
  float yv[4][4];
  if (h == 0) {
#pragma unroll
    for (int i = 0; i < 4; ++i)
#pragma unroll
      for (int j = 0; j < 4; ++j) {
        float s = accY[i][j];
#pragma unroll
        for (int q = 0; q < 7; ++q) s += red[q][u][i * 4 + j];
        yv[i][j] = s;
      }
#pragma unroll
    for (int i = 0; i < 4; ++i)
      *(float4*)&ys[i][u * 4] = make_float4(yv[i][0], yv[i][1], yv[i][2], yv[i][3]);
  }
  __syncthreads();

  float accZ[4][4];
#pragma unroll
  for (int i = 0; i < 4; ++i)
#pragma unroll
    for (int j = 0; j < 4; ++j) accZ[i][j] = 0.f;
#pragma unroll 8
  for (int kk = 0; kk < 32; ++kk) {
    const int k = kb + kk;
    const uint2 aw = *(const uint2*)&Am[k * 256 + u * 4];
    const float b0 = blo(aw.x), b1 = bhi(aw.x), b2 = blo(aw.y), b3 = bhi(aw.y);
    const float y0 = ys[0][k], y1 = ys[1][k], y2 = ys[2][k], y3 = ys[3][k];
    accZ[0][0] += y0 * b0; accZ[0][1] += y0 * b1; accZ[0][2] += y0 * b2; accZ[0][3] += y0 * b3;
    accZ[1][0] += y1 * b0; accZ[1][1] += y1 * b1; accZ[1][2] += y1 * b2; accZ[1][3] += y1 * b3;
    accZ[2][0] += y2 * b0; accZ[2][1] += y2 * b1; accZ[2][2] += y2 * b2; accZ[2][3] += y2 * b3;
    accZ[3][0] += y3 * b0; accZ[3][1] += y3 * b1; accZ[3][2] += y3 * b2; accZ[3][3] += y3 * b3;
  }
  if (h) {
    float* rr = &red[h - 1][u][0];
#pragma unroll
    for (int i = 0; i < 4; ++i)
#pragma unroll
      for (int j = 0; j < 4; ++j) rr[i * 4 + j] = accZ[i][j];
  }
  __syncthreads();
  if (h == 0) {
#pragma unroll
    for (int i = 0; i < 4; ++i) {
      float o[4];
#pragma unroll
      for (int j = 0; j < 4; ++j) {
        float z = accZ[i][j];
#pragma unroll
        for (int q = 0; q < 7; ++q) z += red[q][u][i * 4 + j];
        o[j] = ca * xs[i][u * 4 + j] + cb * yv[i][j] + cc * z;
      }
      *(float4*)&Xo[(i0 + i) * 256 + u * 4] = make_float4(o[0], o[1], o[2], o[3]);
    }
  }
}

// ---------------- K4: output assembly ----------------
__global__ __launch_bounds__(256) void k_out(const float* __restrict__ sp,
                                             const float* __restrict__ P,
                                             const int* __restrict__ sel,
                                             float* __restrict__ out) {
  const int t = threadIdx.x;
  if (blockIdx.x < 128) {
    const int b = blockIdx.x;
    __shared__ float hd[256];
    hd[t] = sp[(size_t)b * Kd + t];
    __syncthreads();
    const int s = sel[b];
    if (s < 0) {
      out[(size_t)b * Kd + t] = hd[t];
    } else {
      const float4* prow = (const float4*)(P + (size_t)s * MSZ + t * 256);
      float acc = 0.f;
#pragma unroll 8
      for (int j4 = 0; j4 < 64; ++j4) {
        const float4 p = prow[j4];
        acc += p.x * hd[4 * j4 + 0] + p.y * hd[4 * j4 + 1] +
               p.z * hd[4 * j4 + 2] + p.w * hd[4 * j4 + 3];
      }
      out[(size_t)b * Kd + t] = hd[t] + 0.1f * acc;
    }
  } else {
    const int ci = blockIdx.x - 128;
    const float4* in4 = (const float4*)sp;
    float4* out4 = (float4*)out;
    const int total = Bn * (Kd / 4);
    for (int i = ci * 256 + t; i < total; i += 2048 * 256) {
      const int pos = i & ((Kd / 4) - 1);
      if (pos >= Qd / 4) out4[i] = in4[i];
    }
  }
}

// ---------------- host ----------------
extern "C" void kernel_launch(void* const* d_in, const int* in_sizes, int n_in,
                              void* d_out, int out_size, void* d_ws, size_t ws_size,
                              hipStream_t stream) {
  (void)in_sizes; (void)n_in; (void)out_size; (void)ws_size;
  const float* sp = (const float*)d_in[0];
  const float* W1 = (const float*)d_in[1];
  const float* b1 = (const float*)d_in[2];
  const float* W2 = (const float*)d_in[3];
  const float* b2 = (const float*)d_in[4];
  const float* W3 = (const float*)d_in[5];
  const float* b3 = (const float*)d_in[6];
  const float* ops = (const float*)d_in[7];
  float* out = (float*)d_out;
  float* ws = (float*)d_ws;

  float* h1p  = ws + OFF_H1P;
  float* h1   = ws + OFF_H1;
  int*   sel  = (int*)(ws + OFF_SEL);
  float* part = ws + OFF_PART;
  float* Xa   = ws + OFF_XA;
  float* Xb   = ws + OFF_XB;
  unsigned short* Ab = (unsigned short*)(ws + OFF_AB);

  k_gemm1<<<NCH, 512, 0, stream>>>(sp, W1, h1p);
  k_red<<<256, 256, 0, stream>>>(h1p, b1, h1);
  k_mlp<<<8, 256, 0, stream>>>(h1, W2, b2, W3, b3, sel);

  // iteration 0 on raw C (scale folded via trace partials)
  k_pA<<<NM * 36, 512, 0, stream>>>(ops, Ab, part);
  k_pB<<<192, 512, 0, stream>>>(ops, Ab, part, Xa, MA, MB, MC, 1);

  float* X = Xa;
  float* Xn = Xb;
  for (int it = 1; it < 11; ++it) {  // 8 Muon total (0..7), then 3 convergent (8..10)
    const bool conv = (it >= 8);
    k_pA<<<NM * 36, 512, 0, stream>>>(X, Ab, part);
    k_pB<<<192, 512, 0, stream>>>(X, Ab, part, Xn,
                                  conv ? CA : MA, conv ? CB : MB, conv ? CC : MC, 0);
    float* tmp = X; X = Xn; Xn = tmp;
  }

  k_out<<<128 + 2048, 256, 0, stream>>>(sp, X, sel, out);
}

// Round 7
// 221.454 us; speedup vs baseline: 1.6157x; 1.1103x over previous
//
#include <hip/hip_runtime.h>
#include <math.h>

// ---------------- problem constants ----------------
constexpr int Bn  = 128;
constexpr int Kd  = 65536;    // magnitude dim (phase half of feats is zeros)
constexpr int F1  = 128;
constexpr int F2  = 64;
constexpr int NM  = 3;
constexpr int Qd  = 256;
constexpr int NCH = 256;      // split-K chunks for big GEMM
constexpr int KC  = 256;
constexpr int MSZ = 256 * 256;

// Muon (growth) and convergent quintic Newton-Schulz coefficients
#define MA 3.4445f
#define MB (-4.7750f)
#define MC 2.0315f
#define CA 1.875f
#define CB (-1.25f)
#define CC 0.375f

// ---------------- ws layout (float offsets) ----------------
constexpr size_t OFF_H1P  = 0;                                   // 4,194,304
constexpr size_t OFF_H1   = OFF_H1P + (size_t)NCH * Bn * F1;
constexpr size_t OFF_SEL  = OFF_H1 + (size_t)Bn * F1;
constexpr size_t OFF_PART = OFF_SEL + 128;
constexpr size_t OFF_XA   = OFF_PART + 64;
constexpr size_t OFF_XB   = OFF_XA + (size_t)NM * MSZ;
constexpr size_t OFF_ACP  = OFF_XB + (size_t)NM * MSZ;           // u32: NM*128*256

// ---------------- f16 helpers ----------------
typedef __fp16 half2_t __attribute__((ext_vector_type(2)));
union HU { half2_t h; unsigned int u; };
__device__ __forceinline__ unsigned int pkh(float x, float y) {
  HU v; v.h = __builtin_amdgcn_cvt_pkrtz(x, y); return v.u;
}
__device__ __forceinline__ half2_t uh(unsigned int u) { HU v; v.u = u; return v.h; }

#if __has_builtin(__builtin_amdgcn_fdot2)
#define FDOT2(a, b, c) __builtin_amdgcn_fdot2((a), (b), (c), false)
#else
#define FDOT2(a, b, c) ((c) + (float)(a)[0] * (float)(b)[0] + (float)(a)[1] * (float)(b)[1])
#endif

// ---------------- K1: split-K magnitude GEMM (LDS double-buffered) ----------------
// 256 blocks x 512 thr; block = k-chunk of 256; 8 subtiles of 32 k; one barrier/subtile.
__global__ __launch_bounds__(512) void k_gemm1(const float* __restrict__ sp,
                                               const float* __restrict__ W1,
                                               float* __restrict__ h1p) {
  __shared__ union SM {
    float stage[2][2][32][132];   // [buf][A/W][k][rowcol]
    float comb[256][65];
  } sm;
  const int t  = threadIdx.x;
  const int ch = blockIdx.x;
  const size_t k0 = (size_t)ch * KC;
  const int u = t & 255;
  const int h = t >> 8;            // k-half within subtile
  const int r0 = (u >> 4) * 4;     // rows {r0, r0+64}
  const int c0 = (u & 15) * 4;     // cols {c0, c0+64}
  const int srow = t >> 3;
  const int squad = t & 7;

  float acc[2][2][4][4];
#pragma unroll
  for (int ri = 0; ri < 2; ++ri)
#pragma unroll
    for (int ci = 0; ci < 2; ++ci)
#pragma unroll
      for (int i = 0; i < 4; ++i)
#pragma unroll
        for (int j = 0; j < 4; ++j) acc[ri][ci][i][j] = 0.f;

  float4 ra0, ra1, rw0, rw1;
  {
    const size_t kb = k0 + squad * 4;
    ra0 = *(const float4*)(sp + (size_t)srow * Kd + kb);
    ra1 = *(const float4*)(sp + (size_t)(srow + 64) * Kd + kb);
    rw0 = *(const float4*)(W1 + (size_t)srow * (2 * Kd) + kb);
    rw1 = *(const float4*)(W1 + (size_t)(srow + 64) * (2 * Kd) + kb);
  }
  // write subtile 0 into buf 0
#pragma unroll
  for (int e = 0; e < 4; ++e) {
    sm.stage[0][0][squad * 4 + e][srow]      = fabsf((&ra0.x)[e]);
    sm.stage[0][0][squad * 4 + e][srow + 64] = fabsf((&ra1.x)[e]);
    sm.stage[0][1][squad * 4 + e][srow]      = (&rw0.x)[e];
    sm.stage[0][1][squad * 4 + e][srow + 64] = (&rw1.x)[e];
  }
  __syncthreads();

#pragma unroll
  for (int kt = 0; kt < 8; ++kt) {
    const int cur = kt & 1;
    if (kt < 7) {   // issue next-subtile loads; land during compute
      const size_t kb = k0 + (kt + 1) * 32 + squad * 4;
      ra0 = *(const float4*)(sp + (size_t)srow * Kd + kb);
      ra1 = *(const float4*)(sp + (size_t)(srow + 64) * Kd + kb);
      rw0 = *(const float4*)(W1 + (size_t)srow * (2 * Kd) + kb);
      rw1 = *(const float4*)(W1 + (size_t)(srow + 64) * (2 * Kd) + kb);
    }
    const float (*As)[132] = sm.stage[cur][0];
    const float (*Ws)[132] = sm.stage[cur][1];
#pragma unroll
    for (int qq = 0; qq < 16; ++qq) {
      const int q = h * 16 + qq;
      const float4 a0 = *(const float4*)&As[q][r0];
      const float4 a1 = *(const float4*)&As[q][r0 + 64];
      const float4 w0 = *(const float4*)&Ws[q][c0];
      const float4 w1 = *(const float4*)&Ws[q][c0 + 64];
      const float av[2][4] = {{a0.x, a0.y, a0.z, a0.w}, {a1.x, a1.y, a1.z, a1.w}};
      const float wv[2][4] = {{w0.x, w0.y, w0.z, w0.w}, {w1.x, w1.y, w1.z, w1.w}};
#pragma unroll
      for (int ri = 0; ri < 2; ++ri)
#pragma unroll
        for (int ci = 0; ci < 2; ++ci)
#pragma unroll
          for (int i = 0; i < 4; ++i)
#pragma unroll
            for (int j = 0; j < 4; ++j)
              acc[ri][ci][i][j] += av[ri][i] * wv[ci][j];
    }
    if (kt < 7) {   // write next subtile into the other buffer (no hazard)
      const int nxt = cur ^ 1;
#pragma unroll
      for (int e = 0; e < 4; ++e) {
        sm.stage[nxt][0][squad * 4 + e][srow]      = fabsf((&ra0.x)[e]);
        sm.stage[nxt][0][squad * 4 + e][srow + 64] = fabsf((&ra1.x)[e]);
        sm.stage[nxt][1][squad * 4 + e][srow]      = (&rw0.x)[e];
        sm.stage[nxt][1][squad * 4 + e][srow + 64] = (&rw1.x)[e];
      }
    }
    __syncthreads();
  }

  // combine k-halves: single round through comb (2-way banks via 65 stride)
  float* af = &acc[0][0][0][0];
  if (h == 1) {
#pragma unroll
    for (int p = 0; p < 64; ++p) sm.comb[u][p] = af[p];
  }
  __syncthreads();
  if (h == 0) {
#pragma unroll
    for (int p = 0; p < 64; ++p) af[p] += sm.comb[u][p];
    float* outp = h1p + (size_t)ch * (Bn * F1);
#pragma unroll
    for (int ri = 0; ri < 2; ++ri)
#pragma unroll
      for (int i = 0; i < 4; ++i) {
        const int row = r0 + ri * 64 + i;
#pragma unroll
        for (int ci = 0; ci < 2; ++ci)
          *(float4*)&outp[row * F1 + c0 + ci * 64] =
              make_float4(acc[ri][ci][i][0], acc[ri][ci][i][1],
                          acc[ri][ci][i][2], acc[ri][ci][i][3]);
      }
  }
}

// ---------------- K1b: reduce partials + bias + relu ----------------
__global__ __launch_bounds__(256) void k_red(const float* __restrict__ h1p,
                                             const float* __restrict__ b1,
                                             float* __restrict__ h1) {
  const int t = threadIdx.x;
  const int ol = t & 63;
  const int g = t >> 6;
  const int o = blockIdx.x * 64 + ol;
  double s = 0.0;
#pragma unroll 8
  for (int c = g * 64; c < g * 64 + 64; ++c)
    s += (double)h1p[(size_t)c * (Bn * F1) + o];
  __shared__ double red[4][64];
  red[g][ol] = s;
  __syncthreads();
  if (g == 0) {
    const double v = red[0][ol] + red[1][ol] + red[2][ol] + red[3][ol];
    const float r = (float)v + b1[o & 127];
    h1[o] = fmaxf(r, 0.f);
  }
}

// ---------------- K2: small MLP + syndrome + selection ----------------
__global__ __launch_bounds__(256) void k_mlp(const float* __restrict__ h1,
                                             const float* __restrict__ W2,
                                             const float* __restrict__ b2,
                                             const float* __restrict__ W3,
                                             const float* __restrict__ b3,
                                             int* __restrict__ sel) {
  const int t = threadIdx.x;
  const int b0 = blockIdx.x * 16;
  __shared__ float h2s[16 * 64];
  for (int o = t; o < 16 * 64; o += 256) {
    const int bl = o >> 6, j = o & 63;
    const float* hr = h1 + (b0 + bl) * F1;
    const float* wr = W2 + j * F1;
    float s = b2[j];
    for (int k = 0; k < F1; ++k) s += hr[k] * wr[k];
    h2s[o] = fmaxf(s, 0.f);
  }
  __syncthreads();
  if (t < 16) {
    const int b = b0 + t;
    float best = -1.f;
    int bi = 0;
    bool needed = false;
    for (int j = 0; j < 8; ++j) {
      double s = (double)b3[j];
      const float* wr = W3 + j * F2;
      for (int k = 0; k < F2; ++k) s += (double)h2s[t * F2 + k] * (double)wr[k];
      const float a = fabsf((float)s);
      if (a > 1e-4f) needed = true;
      if (a > best) { best = a; bi = j; }
    }
    sel[b] = needed ? (bi % NM) : -1;
  }
}

// ---------------- NS phase A: A = X^T X -> f16 colpk (symmetric 32x32 tiles) ----------------
// grid = NM*36 (upper tiles), 512 thr, 8-way k-split. colpk[kp][c] = half2(A[2kp][c], A[2kp+1][c]).
// Diagonal tiles emit trace partials (iter-0 scale).
__global__ __launch_bounds__(512) void k_pA(const float* __restrict__ Xs,
                                            unsigned int* __restrict__ Acp,
                                            float* __restrict__ part) {
  const int bid = blockIdx.x;
  const int m = bid / 36;
  int rem = bid % 36;
  int I = 0;
  while (rem >= 8 - I) { rem -= 8 - I; ++I; }
  const int J = I + rem;
  const float* Xm = Xs + (size_t)m * MSZ;
  unsigned int* Am = Acp + (size_t)m * (128 * 256);
  __shared__ float PI[32][260];
  __shared__ float PJb[32][260];
  __shared__ float red[7][64][17];
  __shared__ float tr8[8];
  float (*PJ)[260] = (I == J) ? PI : PJb;
  const int t = threadIdx.x;

  // stage panels fp32: task = (k, c4-group)
#pragma unroll
  for (int it = 0; it < 4; ++it) {
    const int task = it * 512 + t;
    const int k = task >> 3, c4 = task & 7;
    const float4 vI = *(const float4*)&Xm[k * 256 + I * 32 + c4 * 4];
#pragma unroll
    for (int e = 0; e < 4; ++e) PI[c4 * 4 + e][k] = (&vI.x)[e];
    if (I != J) {
      const float4 vJ = *(const float4*)&Xm[k * 256 + J * 32 + c4 * 4];
#pragma unroll
      for (int e = 0; e < 4; ++e) PJb[c4 * 4 + e][k] = (&vJ.x)[e];
    }
  }
  __syncthreads();

  const int h = t >> 6, u = t & 63, ur = u >> 3, uc = u & 7;
  float a[4][4];
#pragma unroll
  for (int i = 0; i < 4; ++i)
#pragma unroll
    for (int j = 0; j < 4; ++j) a[i][j] = 0.f;

  const int kb = h * 32;
#pragma unroll 8
  for (int kk = 0; kk < 32; ++kk) {
    const int k = kb + kk;
    float xi[4], xj[4];
#pragma unroll
    for (int i = 0; i < 4; ++i) xi[i] = PI[ur * 4 + i][k];
#pragma unroll
    for (int j = 0; j < 4; ++j) xj[j] = PJ[uc * 4 + j][k];
#pragma unroll
    for (int i = 0; i < 4; ++i)
#pragma unroll
      for (int j = 0; j < 4; ++j) a[i][j] += xi[i] * xj[j];
  }
  if (h) {
    float* rr = &red[h - 1][u][0];
#pragma unroll
    for (int i = 0; i < 4; ++i)
#pragma unroll
      for (int j = 0; j < 4; ++j) rr[i * 4 + j] = a[i][j];
  }
  __syncthreads();
  if (h == 0) {
#pragma unroll
    for (int i = 0; i < 4; ++i)
#pragma unroll
      for (int j = 0; j < 4; ++j) {
        float s = a[i][j];
#pragma unroll
        for (int q = 0; q < 7; ++q) s += red[q][u][i * 4 + j];
        a[i][j] = s;
      }
    const int gr = I * 32 + ur * 4, gc = J * 32 + uc * 4;
    // main patch: rows gr.., cols gc.. -> colpk rows gr>>1, gr>>1+1
    {
      const int kp = gr >> 1;
      *(uint4*)&Am[kp * 256 + gc] =
          make_uint4(pkh(a[0][0], a[1][0]), pkh(a[0][1], a[1][1]),
                     pkh(a[0][2], a[1][2]), pkh(a[0][3], a[1][3]));
      *(uint4*)&Am[(kp + 1) * 256 + gc] =
          make_uint4(pkh(a[2][0], a[3][0]), pkh(a[2][1], a[3][1]),
                     pkh(a[2][2], a[3][2]), pkh(a[2][3], a[3][3]));
    }
    if (I != J) {  // mirror patch: rows gc.., cols gr..
      const int kp = gc >> 1;
      *(uint4*)&Am[kp * 256 + gr] =
          make_uint4(pkh(a[0][0], a[0][1]), pkh(a[1][0], a[1][1]),
                     pkh(a[2][0], a[2][1]), pkh(a[3][0], a[3][1]));
      *(uint4*)&Am[(kp + 1) * 256 + gr] =
          make_uint4(pkh(a[0][2], a[0][3]), pkh(a[1][2], a[1][3]),
                     pkh(a[2][2], a[2][3]), pkh(a[3][2], a[3][3]));
    } else if (ur == uc) {
      tr8[ur] = a[0][0] + a[1][1] + a[2][2] + a[3][3];
    }
  }
  if (I == J) {
    __syncthreads();
    if (t == 0) {
      float s = 0.f;
#pragma unroll
      for (int q = 0; q < 8; ++q) s += tr8[q];
      part[m * 8 + I] = s;
    }
  }
}

// ---------------- NS phase B: X' = ca*X + cb*(X A) + cc*(X A A), f16 dot2 ----------------
// grid = 192 (4-row strips), 512 thr, 8-way kp-split; A read as colpk uint4 (coalesced).
__global__ __launch_bounds__(512) void k_pB(const float* __restrict__ Xs,
                                            const unsigned int* __restrict__ Acp,
                                            const float* __restrict__ part,
                                            float* __restrict__ Xn,
                                            const float qa, const float qb, const float qc,
                                            const int first) {
  const int m = blockIdx.x >> 6, g = blockIdx.x & 63, i0 = g * 4;
  const float* Xm = Xs + (size_t)m * MSZ;
  const uint4* A4 = (const uint4*)(Acp + (size_t)m * (128 * 256));
  float* Xo = Xn + (size_t)m * MSZ;
  const int t = threadIdx.x, h = t >> 6, u = t & 63;
  __shared__ float xs[4][260];
  __shared__ unsigned int xsp[4][132];
  __shared__ unsigned int ysp[4][132];
  __shared__ float red[7][64][17];

  float ca = qa, cb = qb, cc = qc;
  if (first) {
    float tr = 0.f;
#pragma unroll
    for (int q = 0; q < 8; ++q) tr += part[m * 8 + q];
    const float s = 0.15f * sqrtf(tr);     // 1.2 * 2*||C||_F/sqrt(256)
    const float is = 1.f / s, is2 = is * is;
    ca = qa * is;
    cb = qb * is * is2;
    cc = qc * is * is2 * is2;
  }

  if (t < 256) {  // stage X strip: fp32 + f16 pairs along k
    const int r = t >> 6, c16 = t & 63;
    const float4 v = *(const float4*)&Xm[(i0 + r) * 256 + c16 * 4];
    *(float4*)&xs[r][c16 * 4] = v;
    xsp[r][2 * c16]     = pkh(v.x, v.y);
    xsp[r][2 * c16 + 1] = pkh(v.z, v.w);
  }
  __syncthreads();

  const int kp0 = h * 16;
  float accY[4][4];
#pragma unroll
  for (int i = 0; i < 4; ++i)
#pragma unroll
    for (int j = 0; j < 4; ++j) accY[i][j] = 0.f;
#pragma unroll 8
  for (int kk = 0; kk < 16; ++kk) {
    const int kp = kp0 + kk;
    const uint4 aw = A4[kp * 64 + u];
    const half2_t b0 = uh(aw.x), b1 = uh(aw.y), b2 = uh(aw.z), b3 = uh(aw.w);
#pragma unroll
    for (int r = 0; r < 4; ++r) {
      const half2_t xp = uh(xsp[r][kp]);
      accY[r][0] = FDOT2(xp, b0, accY[r][0]);
      accY[r][1] = FDOT2(xp, b1, accY[r][1]);
      accY[r][2] = FDOT2(xp, b2, accY[r][2]);
      accY[r][3] = FDOT2(xp, b3, accY[r][3]);
    }
  }
  if (h) {
    float* rr = &red[h - 1][u][0];
#pragma unroll
    for (int i = 0; i < 4; ++i)
#pragma unroll
      for (int j = 0; j < 4; ++j) rr[i * 4 + j] = accY[i][j];
  }
  __syncthreads();
  float yv[4][4];
  if (h == 0) {
#pragma unroll
    for (int i = 0; i < 4; ++i)
#pragma unroll
      for (int j = 0; j < 4; ++j) {
        float s = accY[i][j];
#pragma unroll
        for (int q = 0; q < 7; ++q) s += red[q][u][i * 4 + j];
        yv[i][j] = s;
      }
#pragma unroll
    for (int i = 0; i < 4; ++i) {
      ysp[i][2 * u]     = pkh(yv[i][0], yv[i][1]);
      ysp[i][2 * u + 1] = pkh(yv[i][2], yv[i][3]);
    }
  }
  __syncthreads();

  float accZ[4][4];
#pragma unroll
  for (int i = 0; i < 4; ++i)
#pragma unroll
    for (int j = 0; j < 4; ++j) accZ[i][j] = 0.f;
#pragma unroll 8
  for (int kk = 0; kk < 16; ++kk) {
    const int kp = kp0 + kk;
    const uint4 aw = A4[kp * 64 + u];
    const half2_t b0 = uh(aw.x), b1 = uh(aw.y), b2 = uh(aw.z), b3 = uh(aw.w);
#pragma unroll
    for (int r = 0; r < 4; ++r) {
      const half2_t yp = uh(ysp[r][kp]);
      accZ[r][0] = FDOT2(yp, b0, accZ[r][0]);
      accZ[r][1] = FDOT2(yp, b1, accZ[r][1]);
      accZ[r][2] = FDOT2(yp, b2, accZ[r][2]);
      accZ[r][3] = FDOT2(yp, b3, accZ[r][3]);
    }
  }
  if (h) {
    float* rr = &red[h - 1][u][0];
#pragma unroll
    for (int i = 0; i < 4; ++i)
#pragma unroll
      for (int j = 0; j < 4; ++j) rr[i * 4 + j] = accZ[i][j];
  }
  __syncthreads();
  if (h == 0) {
#pragma unroll
    for (int i = 0; i < 4; ++i) {
      float o[4];
#pragma unroll
      for (int j = 0; j < 4; ++j) {
        float z = accZ[i][j];
#pragma unroll
        for (int q = 0; q < 7; ++q) z += red[q][u][i * 4 + j];
        o[j] = ca * xs[i][u * 4 + j] + cb * yv[i][j] + cc * z;
      }
      *(float4*)&Xo[(i0 + i) * 256 + u * 4] = make_float4(o[0], o[1], o[2], o[3]);
    }
  }
}

// ---------------- K4: output assembly ----------------
__global__ __launch_bounds__(256) void k_out(const float* __restrict__ sp,
                                             const float* __restrict__ P,
                                             const int* __restrict__ sel,
                                             float* __restrict__ out) {
  const int t = threadIdx.x;
  if (blockIdx.x < 128) {
    const int b = blockIdx.x;
    __shared__ float hd[256];
    hd[t] = sp[(size_t)b * Kd + t];
    __syncthreads();
    const int s = sel[b];
    if (s < 0) {
      out[(size_t)b * Kd + t] = hd[t];
    } else {
      const float4* prow = (const float4*)(P + (size_t)s * MSZ + t * 256);
      float acc = 0.f;
#pragma unroll 8
      for (int j4 = 0; j4 < 64; ++j4) {
        const float4 p = prow[j4];
        acc += p.x * hd[4 * j4 + 0] + p.y * hd[4 * j4 + 1] +
               p.z * hd[4 * j4 + 2] + p.w * hd[4 * j4 + 3];
      }
      out[(size_t)b * Kd + t] = hd[t] + 0.1f * acc;
    }
  } else {
    const int ci = blockIdx.x - 128;
    const float4* in4 = (const float4*)sp;
    float4* out4 = (float4*)out;
    const int total = Bn * (Kd / 4);
    for (int i = ci * 256 + t; i < total; i += 2048 * 256) {
      const int pos = i & ((Kd / 4) - 1);
      if (pos >= Qd / 4) out4[i] = in4[i];
    }
  }
}

// ---------------- host ----------------
extern "C" void kernel_launch(void* const* d_in, const int* in_sizes, int n_in,
                              void* d_out, int out_size, void* d_ws, size_t ws_size,
                              hipStream_t stream) {
  (void)in_sizes; (void)n_in; (void)out_size; (void)ws_size;
  const float* sp = (const float*)d_in[0];
  const float* W1 = (const float*)d_in[1];
  const float* b1 = (const float*)d_in[2];
  const float* W2 = (const float*)d_in[3];
  const float* b2 = (const float*)d_in[4];
  const float* W3 = (const float*)d_in[5];
  const float* b3 = (const float*)d_in[6];
  const float* ops = (const float*)d_in[7];
  float* out = (float*)d_out;
  float* ws = (float*)d_ws;

  float* h1p  = ws + OFF_H1P;
  float* h1   = ws + OFF_H1;
  int*   sel  = (int*)(ws + OFF_SEL);
  float* part = ws + OFF_PART;
  float* Xa   = ws + OFF_XA;
  float* Xb   = ws + OFF_XB;
  unsigned int* Acp = (unsigned int*)(ws + OFF_ACP);

  k_gemm1<<<NCH, 512, 0, stream>>>(sp, W1, h1p);
  k_red<<<256, 256, 0, stream>>>(h1p, b1, h1);
  k_mlp<<<8, 256, 0, stream>>>(h1, W2, b2, W3, b3, sel);

  // iteration 0 on raw C (scale folded via trace partials)
  k_pA<<<NM * 36, 512, 0, stream>>>(ops, Acp, part);
  k_pB<<<192, 512, 0, stream>>>(ops, Acp, part, Xa, MA, MB, MC, 1);

  float* X = Xa;
  float* Xn = Xb;
  for (int it = 1; it < 10; ++it) {  // its 0..7 Muon (8), 8..9 convergent (2)
    const bool conv = (it >= 8);
    k_pA<<<NM * 36, 512, 0, stream>>>(X, Acp, part);
    k_pB<<<192, 512, 0, stream>>>(X, Acp, part, Xn,
                                  conv ? CA : MA, conv ? CB : MB, conv ? CC : MC, 0);
    float* tmp = X; X = Xn; Xn = tmp;
  }

  k_out<<<128 + 2048, 256, 0, stream>>>(sp, X, sel, out);
}